// Round 12
// baseline (548.231 us; speedup 1.0000x reference)
//
#include <hip/hip_runtime.h>
#include <math.h>

#define BATCH 32
#define CH 768
#define HW 3136            // 56*56
#define HW4 (HW/4)         // 784 float4 = 3*256 + 16
#define HID 48
#define PLANES (BATCH*CH)  // 24576
#define BPI 192            // blocks per image (768 planes / 4 planes-per-block)
#define NBLK (BATCH*BPI)   // 6144
#define PAD 32             // counter padding (ints) to avoid false sharing

typedef float nfloat4 __attribute__((ext_vector_type(4)));

__global__ __launch_bounds__(256, 8) void cbam_onekernel(
    const float* __restrict__ x,
    const float* __restrict__ w1,   // [HID, CH]
    const float* __restrict__ w2,   // [CH, HID]
    float* __restrict__ out,
    float* __restrict__ avg,
    float* __restrict__ mx,
    float* __restrict__ gate,
    int* __restrict__ cnt,          // BATCH counters (stride PAD), zeroed per call
    int* __restrict__ flag)         // BATCH flags   (stride PAD), zeroed per call
{
    const int g    = blockIdx.x;
    const int img  = g / BPI;
    const int sub  = g % BPI;
    const int wave = threadIdx.x >> 6;
    const int lane = threadIdx.x & 63;
    const int plane = img * CH + sub * 4 + wave;   // 4 consecutive planes per block

    __shared__ float sa[CH];
    __shared__ float sv[CH];
    __shared__ float ha[HID];
    __shared__ float hm[HID];
    __shared__ float hsum[HID];
    __shared__ int   sIsLast;

    // ---------------- Phase 1: pool own plane (one plane per wave) ----------------
    {
        const nfloat4* xp = reinterpret_cast<const nfloat4*>(x + (size_t)plane * HW);
        float s = 0.0f;
        float m = -INFINITY;
        #pragma unroll
        for (int j = 0; j < 3; ++j) {
            const int base = j * 256 + lane;
            nfloat4 a = xp[base];
            nfloat4 b = xp[base + 64];
            nfloat4 c = xp[base + 128];
            nfloat4 d = xp[base + 192];
            s += ((a.x + a.y) + (a.z + a.w)) + ((b.x + b.y) + (b.z + b.w))
               + ((c.x + c.y) + (c.z + c.w)) + ((d.x + d.y) + (d.z + d.w));
            float ma = fmaxf(fmaxf(a.x, a.y), fmaxf(a.z, a.w));
            float mb = fmaxf(fmaxf(b.x, b.y), fmaxf(b.z, b.w));
            float mc = fmaxf(fmaxf(c.x, c.y), fmaxf(c.z, c.w));
            float md = fmaxf(fmaxf(d.x, d.y), fmaxf(d.z, d.w));
            m = fmaxf(m, fmaxf(fmaxf(ma, mb), fmaxf(mc, md)));
        }
        if (lane < 16) {
            nfloat4 a = xp[768 + lane];
            s += (a.x + a.y) + (a.z + a.w);
            m = fmaxf(m, fmaxf(fmaxf(a.x, a.y), fmaxf(a.z, a.w)));
        }
        for (int off = 32; off > 0; off >>= 1) {
            s += __shfl_down(s, off, 64);
            m = fmaxf(m, __shfl_down(m, off, 64));
        }
        if (lane == 0) {
            // coherent (agent-scope) stores: visible at the coherence point, no fences needed
            __hip_atomic_store(&avg[plane], s * (1.0f / (float)HW),
                               __ATOMIC_RELAXED, __HIP_MEMORY_SCOPE_AGENT);
            __hip_atomic_store(&mx[plane], m,
                               __ATOMIC_RELAXED, __HIP_MEMORY_SCOPE_AGENT);
        }
    }

    // ---------------- Election: last block of this image computes the MLP ----------------
    __syncthreads();                 // drains vmcnt -> all 4 waves' sc1 stores complete
    if (threadIdx.x == 0) {
        int old = __hip_atomic_fetch_add(&cnt[img * PAD], 1,
                                         __ATOMIC_ACQ_REL, __HIP_MEMORY_SCOPE_AGENT);
        sIsLast = (old == BPI - 1);
    }
    __syncthreads();

    if (sIsLast) {
        // ---- MLP for this image (one block, ~110K MACs) ----
        for (int i = threadIdx.x; i < CH; i += 256) {
            sa[i] = __hip_atomic_load(&avg[img * CH + i], __ATOMIC_RELAXED, __HIP_MEMORY_SCOPE_AGENT);
            sv[i] = __hip_atomic_load(&mx[img * CH + i],  __ATOMIC_RELAXED, __HIP_MEMORY_SCOPE_AGENT);
        }
        __syncthreads();

        if (threadIdx.x < 2 * HID) {
            const bool is_avg = threadIdx.x < HID;
            const int h = is_avg ? threadIdx.x : threadIdx.x - HID;
            const float4* in4 = reinterpret_cast<const float4*>(is_avg ? sa : sv);
            const float4* wr4 = reinterpret_cast<const float4*>(w1 + (size_t)h * CH);
            float acc = 0.0f;
            #pragma unroll 8
            for (int k = 0; k < CH / 4; ++k) {
                float4 a = in4[k];
                float4 w = wr4[k];
                acc += a.x * w.x + a.y * w.y + a.z * w.z + a.w * w.w;
            }
            float ge = 0.5f * acc * (1.0f + erff(acc * 0.70710678118654752f));
            if (is_avg) ha[h] = ge; else hm[h] = ge;
        }
        __syncthreads();
        if (threadIdx.x < HID) hsum[threadIdx.x] = ha[threadIdx.x] + hm[threadIdx.x];
        __syncthreads();

        for (int c = threadIdx.x; c < CH; c += 256) {
            const float4* wr4 = reinterpret_cast<const float4*>(w2 + (size_t)c * HID);
            const float4* hs4 = reinterpret_cast<const float4*>(hsum);
            float acc = 0.0f;
            #pragma unroll
            for (int h = 0; h < HID / 4; ++h) {
                float4 a = hs4[h];
                float4 w = wr4[h];
                acc += a.x * w.x + a.y * w.y + a.z * w.z + a.w * w.w;
            }
            __hip_atomic_store(&gate[img * CH + c], 1.0f / (1.0f + expf(-acc)),
                               __ATOMIC_RELAXED, __HIP_MEMORY_SCOPE_AGENT);
        }
        __syncthreads();             // drain gate stores before releasing the flag
        if (threadIdx.x == 0) {
            __hip_atomic_store(&flag[img * PAD], 1,
                               __ATOMIC_RELEASE, __HIP_MEMORY_SCOPE_AGENT);
        }
    }

    // ---------------- Wait for this image's gate (relaxed poll, no invalidate storm) ----------------
    if (threadIdx.x == 0) {
        while (__hip_atomic_load(&flag[img * PAD], __ATOMIC_RELAXED, __HIP_MEMORY_SCOPE_AGENT) == 0) {
            __builtin_amdgcn_s_sleep(16);
        }
        (void)__hip_atomic_load(&flag[img * PAD], __ATOMIC_ACQUIRE, __HIP_MEMORY_SCOPE_AGENT);
    }
    __syncthreads();

    // ---------------- Phase 3: scale own plane (L3-hot re-read), nt stores ----------------
    {
        float gv = 0.0f;
        if (lane == 0)
            gv = __hip_atomic_load(&gate[plane], __ATOMIC_RELAXED, __HIP_MEMORY_SCOPE_AGENT);
        gv = __shfl(gv, 0, 64);

        const nfloat4* xp = reinterpret_cast<const nfloat4*>(x + (size_t)plane * HW);
        nfloat4* op = reinterpret_cast<nfloat4*>(out + (size_t)plane * HW);
        #pragma unroll
        for (int j = 0; j < 3; ++j) {
            const int base = j * 256 + lane;
            nfloat4 a = xp[base];
            nfloat4 b = xp[base + 64];
            nfloat4 c = xp[base + 128];
            nfloat4 d = xp[base + 192];
            a.x *= gv; a.y *= gv; a.z *= gv; a.w *= gv;
            b.x *= gv; b.y *= gv; b.z *= gv; b.w *= gv;
            c.x *= gv; c.y *= gv; c.z *= gv; c.w *= gv;
            d.x *= gv; d.y *= gv; d.z *= gv; d.w *= gv;
            __builtin_nontemporal_store(a, &op[base]);
            __builtin_nontemporal_store(b, &op[base + 64]);
            __builtin_nontemporal_store(c, &op[base + 128]);
            __builtin_nontemporal_store(d, &op[base + 192]);
        }
        if (lane < 16) {
            const int i = 768 + lane;
            nfloat4 a = xp[i];
            a.x *= gv; a.y *= gv; a.z *= gv; a.w *= gv;
            __builtin_nontemporal_store(a, &op[i]);
        }
    }
}

extern "C" void kernel_launch(void* const* d_in, const int* in_sizes, int n_in,
                              void* d_out, int out_size, void* d_ws, size_t ws_size,
                              hipStream_t stream) {
    const float* x  = (const float*)d_in[0];
    const float* w1 = (const float*)d_in[1];
    const float* w2 = (const float*)d_in[2];
    float* out = (float*)d_out;

    float* avg  = (float*)d_ws;                 // PLANES floats
    float* mx   = avg + PLANES;                 // PLANES floats
    float* gate = mx + PLANES;                  // PLANES floats
    int*   cnt  = (int*)(gate + PLANES);        // BATCH*PAD ints
    int*   flag = cnt + BATCH * PAD;            // BATCH*PAD ints

    // zero the handshake state every call (graph-capture-safe)
    hipMemsetAsync(cnt, 0, 2 * BATCH * PAD * sizeof(int), stream);

    cbam_onekernel<<<NBLK, 256, 0, stream>>>(x, w1, w2, out, avg, mx, gate, cnt, flag);
}

// Round 13
// 470.740 us; speedup vs baseline: 1.1646x; 1.1646x over previous
//
#include <hip/hip_runtime.h>
#include <math.h>

#define BATCH 32
#define CH 768
#define HW 3136            // 56*56
#define HW4 (HW/4)         // 784 float4 = 3*256 + 16
#define HID 48
#define PLANES (BATCH*CH)  // 24576
#define BPI 192            // blocks per image (768 planes / 4 planes-per-block)
#define HALF_IMGS 16       // images per half: 16 * 9.4 MB = 154 MB < 256 MB L3
#define HBLK (HALF_IMGS*BPI) // 3072 blocks per half-kernel
#define PAD 32             // counter padding (ints)

typedef float nfloat4 __attribute__((ext_vector_type(4)));

// ============ Kernel A: pool 4 planes/block + elected last-block-per-image MLP ============
__global__ __launch_bounds__(256, 8) void cbam_pool_mlp(
    const float* __restrict__ x,
    const float* __restrict__ w1,   // [HID, CH]
    const float* __restrict__ w2,   // [CH, HID]
    float* __restrict__ avg,
    float* __restrict__ mx,
    float* __restrict__ gate,
    int* __restrict__ cnt,          // BATCH counters (stride PAD), zeroed per call
    int img0)
{
    const int img  = img0 + blockIdx.x / BPI;
    const int sub  = blockIdx.x % BPI;
    const int wave = threadIdx.x >> 6;
    const int lane = threadIdx.x & 63;
    const int plane = img * CH + sub * 4 + wave;

    __shared__ float sa[CH];
    __shared__ float sv[CH];
    __shared__ float ha[HID];
    __shared__ float hm[HID];
    __shared__ float hsum[HID];
    __shared__ int   sIsLast;

    // ---- pool own plane (one plane per wave, 4-deep ILP) ----
    {
        const nfloat4* xp = reinterpret_cast<const nfloat4*>(x + (size_t)plane * HW);
        float s = 0.0f;
        float m = -INFINITY;
        #pragma unroll
        for (int j = 0; j < 3; ++j) {
            const int base = j * 256 + lane;
            nfloat4 a = xp[base];
            nfloat4 b = xp[base + 64];
            nfloat4 c = xp[base + 128];
            nfloat4 d = xp[base + 192];
            s += ((a.x + a.y) + (a.z + a.w)) + ((b.x + b.y) + (b.z + b.w))
               + ((c.x + c.y) + (c.z + c.w)) + ((d.x + d.y) + (d.z + d.w));
            float ma = fmaxf(fmaxf(a.x, a.y), fmaxf(a.z, a.w));
            float mb = fmaxf(fmaxf(b.x, b.y), fmaxf(b.z, b.w));
            float mc = fmaxf(fmaxf(c.x, c.y), fmaxf(c.z, c.w));
            float md = fmaxf(fmaxf(d.x, d.y), fmaxf(d.z, d.w));
            m = fmaxf(m, fmaxf(fmaxf(ma, mb), fmaxf(mc, md)));
        }
        if (lane < 16) {
            nfloat4 a = xp[768 + lane];
            s += (a.x + a.y) + (a.z + a.w);
            m = fmaxf(m, fmaxf(fmaxf(a.x, a.y), fmaxf(a.z, a.w)));
        }
        for (int off = 32; off > 0; off >>= 1) {
            s += __shfl_down(s, off, 64);
            m = fmaxf(m, __shfl_down(m, off, 64));
        }
        if (lane == 0) {
            // agent-scope (sc1) stores: coherent across XCDs for the elected reader
            __hip_atomic_store(&avg[plane], s * (1.0f / (float)HW),
                               __ATOMIC_RELAXED, __HIP_MEMORY_SCOPE_AGENT);
            __hip_atomic_store(&mx[plane], m,
                               __ATOMIC_RELAXED, __HIP_MEMORY_SCOPE_AGENT);
        }
    }

    // ---- election: last block of this image computes the MLP; everyone else exits ----
    __syncthreads();              // drains vmcnt -> this block's sc1 stores are globally visible
    if (threadIdx.x == 0) {
        int old = __hip_atomic_fetch_add(&cnt[img * PAD], 1,
                                         __ATOMIC_ACQ_REL, __HIP_MEMORY_SCOPE_AGENT);
        sIsLast = (old == BPI - 1);
    }
    __syncthreads();
    if (!sIsLast) return;

    // ---- MLP for this image (one block; ~110K MACs) ----
    for (int i = threadIdx.x; i < CH; i += 256) {
        sa[i] = __hip_atomic_load(&avg[img * CH + i], __ATOMIC_RELAXED, __HIP_MEMORY_SCOPE_AGENT);
        sv[i] = __hip_atomic_load(&mx[img * CH + i],  __ATOMIC_RELAXED, __HIP_MEMORY_SCOPE_AGENT);
    }
    __syncthreads();

    if (threadIdx.x < 2 * HID) {
        const bool is_avg = threadIdx.x < HID;
        const int h = is_avg ? threadIdx.x : threadIdx.x - HID;
        const float4* in4 = reinterpret_cast<const float4*>(is_avg ? sa : sv);
        const float4* wr4 = reinterpret_cast<const float4*>(w1 + (size_t)h * CH);
        float acc = 0.0f;
        #pragma unroll 8
        for (int k = 0; k < CH / 4; ++k) {
            float4 a = in4[k];
            float4 w = wr4[k];
            acc += a.x * w.x + a.y * w.y + a.z * w.z + a.w * w.w;
        }
        float ge = 0.5f * acc * (1.0f + erff(acc * 0.70710678118654752f));
        if (is_avg) ha[h] = ge; else hm[h] = ge;
    }
    __syncthreads();
    if (threadIdx.x < HID) hsum[threadIdx.x] = ha[threadIdx.x] + hm[threadIdx.x];
    __syncthreads();

    for (int c = threadIdx.x; c < CH; c += 256) {
        const float4* wr4 = reinterpret_cast<const float4*>(w2 + (size_t)c * HID);
        const float4* hs4 = reinterpret_cast<const float4*>(hsum);
        float acc = 0.0f;
        #pragma unroll
        for (int h = 0; h < HID / 4; ++h) {
            float4 a = hs4[h];
            float4 w = wr4[h];
            acc += a.x * w.x + a.y * w.y + a.z * w.z + a.w * w.w;
        }
        // plain store: kernel-completion release + next-dispatch acquire makes it visible to B
        gate[img * CH + c] = 1.0f / (1.0f + expf(-acc));
    }
}

// ============ Kernel B: scale half's planes (x re-read is L3-hot by construction) ============
__global__ __launch_bounds__(256, 8) void cbam_scale(
    const float* __restrict__ x,
    const float* __restrict__ gate,
    float* __restrict__ out,
    int img0)
{
    const int wave = threadIdx.x >> 6;
    const int lane = threadIdx.x & 63;
    const int plane = img0 * CH + blockIdx.x * 4 + wave;
    const float g = gate[plane];              // same addr across wave -> HW broadcast
    const nfloat4* xp = reinterpret_cast<const nfloat4*>(x + (size_t)plane * HW);
    nfloat4* op = reinterpret_cast<nfloat4*>(out + (size_t)plane * HW);

    #pragma unroll
    for (int j = 0; j < 3; ++j) {
        const int base = j * 256 + lane;
        nfloat4 a = xp[base];
        nfloat4 b = xp[base + 64];
        nfloat4 c = xp[base + 128];
        nfloat4 d = xp[base + 192];
        a.x *= g; a.y *= g; a.z *= g; a.w *= g;
        b.x *= g; b.y *= g; b.z *= g; b.w *= g;
        c.x *= g; c.y *= g; c.z *= g; c.w *= g;
        d.x *= g; d.y *= g; d.z *= g; d.w *= g;
        __builtin_nontemporal_store(a, &op[base]);
        __builtin_nontemporal_store(b, &op[base + 64]);
        __builtin_nontemporal_store(c, &op[base + 128]);
        __builtin_nontemporal_store(d, &op[base + 192]);
    }
    if (lane < 16) {
        const int i = 768 + lane;
        nfloat4 a = xp[i];
        a.x *= g; a.y *= g; a.z *= g; a.w *= g;
        __builtin_nontemporal_store(a, &op[i]);
    }
}

extern "C" void kernel_launch(void* const* d_in, const int* in_sizes, int n_in,
                              void* d_out, int out_size, void* d_ws, size_t ws_size,
                              hipStream_t stream) {
    const float* x  = (const float*)d_in[0];
    const float* w1 = (const float*)d_in[1];
    const float* w2 = (const float*)d_in[2];
    float* out = (float*)d_out;

    float* avg  = (float*)d_ws;                 // PLANES floats
    float* mx   = avg + PLANES;                 // PLANES floats
    float* gate = mx + PLANES;                  // PLANES floats
    int*   cnt  = (int*)(gate + PLANES);        // BATCH*PAD ints

    hipMemsetAsync(cnt, 0, BATCH * PAD * sizeof(int), stream);

    // half 0: images 0..15 (154 MB — fits Infinity Cache), then scale while L3-hot
    cbam_pool_mlp<<<HBLK, 256, 0, stream>>>(x, w1, w2, avg, mx, gate, cnt, 0);
    cbam_scale  <<<HBLK, 256, 0, stream>>>(x, gate, out, 0);
    // half 1: images 16..31
    cbam_pool_mlp<<<HBLK, 256, 0, stream>>>(x, w1, w2, avg, mx, gate, cnt, HALF_IMGS);
    cbam_scale  <<<HBLK, 256, 0, stream>>>(x, gate, out, HALF_IMGS);
}

// Round 14
// 444.278 us; speedup vs baseline: 1.2340x; 1.0596x over previous
//
#include <hip/hip_runtime.h>
#include <math.h>

#define BATCH 32
#define CH 768
#define HW 3136            // 56*56
#define HW4 (HW/4)         // 784 float4 = 3*256 + 16
#define HID 48
#define PLANES (BATCH*CH)  // 24576
#define BPI 192            // blocks per image (768 planes / 4 planes-per-block)
#define HALF_IMGS 16       // images per half: 16 * 9.4 MB = 154 MB < 256 MB L3
#define HBLK (HALF_IMGS*BPI) // 3072 blocks per half-kernel
#define PAD 32             // counter padding (ints)

typedef float nfloat4 __attribute__((ext_vector_type(4)));

// ============ Kernel A: pool 4 planes/block + elected last-block-per-image MLP ============
// NOTE: plain __launch_bounds__(256) — R13's (256,8) capped VGPR at 32 and serialized
// the 4-deep load batching (250us @ 300GB/s). Register budget > occupancy here.
__global__ __launch_bounds__(256) void cbam_pool_mlp(
    const float* __restrict__ x,
    const float* __restrict__ w1,   // [HID, CH]
    const float* __restrict__ w2,   // [CH, HID]
    float* __restrict__ avg,
    float* __restrict__ mx,
    float* __restrict__ gate,
    int* __restrict__ cnt,          // BATCH counters (stride PAD), zeroed per call
    int img0)
{
    const int img  = img0 + blockIdx.x / BPI;
    const int sub  = blockIdx.x % BPI;
    const int wave = threadIdx.x >> 6;
    const int lane = threadIdx.x & 63;
    const int plane = img * CH + sub * 4 + wave;

    __shared__ float sa[CH];
    __shared__ float sv[CH];
    __shared__ float ha[HID];
    __shared__ float hm[HID];
    __shared__ float hsum[HID];
    __shared__ int   sIsLast;

    // ---- pool own plane (one plane per wave, 4-deep ILP) ----
    {
        const nfloat4* xp = reinterpret_cast<const nfloat4*>(x + (size_t)plane * HW);
        float s = 0.0f;
        float m = -INFINITY;
        #pragma unroll
        for (int j = 0; j < 3; ++j) {
            const int base = j * 256 + lane;
            nfloat4 a = xp[base];
            nfloat4 b = xp[base + 64];
            nfloat4 c = xp[base + 128];
            nfloat4 d = xp[base + 192];
            s += ((a.x + a.y) + (a.z + a.w)) + ((b.x + b.y) + (b.z + b.w))
               + ((c.x + c.y) + (c.z + c.w)) + ((d.x + d.y) + (d.z + d.w));
            float ma = fmaxf(fmaxf(a.x, a.y), fmaxf(a.z, a.w));
            float mb = fmaxf(fmaxf(b.x, b.y), fmaxf(b.z, b.w));
            float mc = fmaxf(fmaxf(c.x, c.y), fmaxf(c.z, c.w));
            float md = fmaxf(fmaxf(d.x, d.y), fmaxf(d.z, d.w));
            m = fmaxf(m, fmaxf(fmaxf(ma, mb), fmaxf(mc, md)));
        }
        if (lane < 16) {
            nfloat4 a = xp[768 + lane];
            s += (a.x + a.y) + (a.z + a.w);
            m = fmaxf(m, fmaxf(fmaxf(a.x, a.y), fmaxf(a.z, a.w)));
        }
        for (int off = 32; off > 0; off >>= 1) {
            s += __shfl_down(s, off, 64);
            m = fmaxf(m, __shfl_down(m, off, 64));
        }
        if (lane == 0) {
            // agent-scope (sc1) stores: coherent across XCDs for the elected reader
            __hip_atomic_store(&avg[plane], s * (1.0f / (float)HW),
                               __ATOMIC_RELAXED, __HIP_MEMORY_SCOPE_AGENT);
            __hip_atomic_store(&mx[plane], m,
                               __ATOMIC_RELAXED, __HIP_MEMORY_SCOPE_AGENT);
        }
    }

    // ---- election: last block of this image computes the MLP; everyone else exits ----
    __syncthreads();              // drains vmcnt -> this block's sc1 stores are globally visible
    if (threadIdx.x == 0) {
        int old = __hip_atomic_fetch_add(&cnt[img * PAD], 1,
                                         __ATOMIC_ACQ_REL, __HIP_MEMORY_SCOPE_AGENT);
        sIsLast = (old == BPI - 1);
    }
    __syncthreads();
    if (!sIsLast) return;

    // ---- MLP for this image (one block; ~110K MACs) ----
    for (int i = threadIdx.x; i < CH; i += 256) {
        sa[i] = __hip_atomic_load(&avg[img * CH + i], __ATOMIC_RELAXED, __HIP_MEMORY_SCOPE_AGENT);
        sv[i] = __hip_atomic_load(&mx[img * CH + i],  __ATOMIC_RELAXED, __HIP_MEMORY_SCOPE_AGENT);
    }
    __syncthreads();

    if (threadIdx.x < 2 * HID) {
        const bool is_avg = threadIdx.x < HID;
        const int h = is_avg ? threadIdx.x : threadIdx.x - HID;
        const float4* in4 = reinterpret_cast<const float4*>(is_avg ? sa : sv);
        const float4* wr4 = reinterpret_cast<const float4*>(w1 + (size_t)h * CH);
        float acc = 0.0f;
        #pragma unroll 8
        for (int k = 0; k < CH / 4; ++k) {
            float4 a = in4[k];
            float4 w = wr4[k];
            acc += a.x * w.x + a.y * w.y + a.z * w.z + a.w * w.w;
        }
        float ge = 0.5f * acc * (1.0f + erff(acc * 0.70710678118654752f));
        if (is_avg) ha[h] = ge; else hm[h] = ge;
    }
    __syncthreads();
    if (threadIdx.x < HID) hsum[threadIdx.x] = ha[threadIdx.x] + hm[threadIdx.x];
    __syncthreads();

    for (int c = threadIdx.x; c < CH; c += 256) {
        const float4* wr4 = reinterpret_cast<const float4*>(w2 + (size_t)c * HID);
        const float4* hs4 = reinterpret_cast<const float4*>(hsum);
        float acc = 0.0f;
        #pragma unroll
        for (int h = 0; h < HID / 4; ++h) {
            float4 a = hs4[h];
            float4 w = wr4[h];
            acc += a.x * w.x + a.y * w.y + a.z * w.z + a.w * w.w;
        }
        // plain store: kernel-completion release + next-dispatch acquire makes it visible to B
        gate[img * CH + c] = 1.0f / (1.0f + expf(-acc));
    }
}

// ============ Kernel B: scale half's planes (x re-read is L3-hot by construction) ============
__global__ __launch_bounds__(256) void cbam_scale(
    const float* __restrict__ x,
    const float* __restrict__ gate,
    float* __restrict__ out,
    int img0)
{
    const int wave = threadIdx.x >> 6;
    const int lane = threadIdx.x & 63;
    const int plane = img0 * CH + blockIdx.x * 4 + wave;
    const float g = gate[plane];              // same addr across wave -> HW broadcast
    const nfloat4* xp = reinterpret_cast<const nfloat4*>(x + (size_t)plane * HW);
    nfloat4* op = reinterpret_cast<nfloat4*>(out + (size_t)plane * HW);

    #pragma unroll
    for (int j = 0; j < 3; ++j) {
        const int base = j * 256 + lane;
        nfloat4 a = xp[base];
        nfloat4 b = xp[base + 64];
        nfloat4 c = xp[base + 128];
        nfloat4 d = xp[base + 192];
        a.x *= g; a.y *= g; a.z *= g; a.w *= g;
        b.x *= g; b.y *= g; b.z *= g; b.w *= g;
        c.x *= g; c.y *= g; c.z *= g; c.w *= g;
        d.x *= g; d.y *= g; d.z *= g; d.w *= g;
        __builtin_nontemporal_store(a, &op[base]);
        __builtin_nontemporal_store(b, &op[base + 64]);
        __builtin_nontemporal_store(c, &op[base + 128]);
        __builtin_nontemporal_store(d, &op[base + 192]);
    }
    if (lane < 16) {
        const int i = 768 + lane;
        nfloat4 a = xp[i];
        a.x *= g; a.y *= g; a.z *= g; a.w *= g;
        __builtin_nontemporal_store(a, &op[i]);
    }
}

extern "C" void kernel_launch(void* const* d_in, const int* in_sizes, int n_in,
                              void* d_out, int out_size, void* d_ws, size_t ws_size,
                              hipStream_t stream) {
    const float* x  = (const float*)d_in[0];
    const float* w1 = (const float*)d_in[1];
    const float* w2 = (const float*)d_in[2];
    float* out = (float*)d_out;

    float* avg  = (float*)d_ws;                 // PLANES floats
    float* mx   = avg + PLANES;                 // PLANES floats
    float* gate = mx + PLANES;                  // PLANES floats
    int*   cnt  = (int*)(gate + PLANES);        // BATCH*PAD ints

    hipMemsetAsync(cnt, 0, BATCH * PAD * sizeof(int), stream);

    // half 0: images 0..15 (154 MB — fits Infinity Cache), then scale while L3-hot
    cbam_pool_mlp<<<HBLK, 256, 0, stream>>>(x, w1, w2, avg, mx, gate, cnt, 0);
    cbam_scale  <<<HBLK, 256, 0, stream>>>(x, gate, out, 0);
    // half 1: images 16..31
    cbam_pool_mlp<<<HBLK, 256, 0, stream>>>(x, w1, w2, avg, mx, gate, cnt, HALF_IMGS);
    cbam_scale  <<<HBLK, 256, 0, stream>>>(x, gate, out, HALF_IMGS);
}